// Round 5
// baseline (5373.964 us; speedup 1.0000x reference)
//
#include <hip/hip_runtime.h>

#define T_    8192
#define D_    256
#define E_    8
#define TWOD  512
#define NTOK  16384
#define CAP_  2048
#define NQ    (NTOK * 128)   // float4 count of an (N, 512) fp32 array

// ---------------- init: x_states = x, x_target = phase_targets(x) ----------------
__global__ __launch_bounds__(256) void init_kernel(const float4* __restrict__ x,
    const float* __restrict__ cosp, const float* __restrict__ sinp,
    float4* __restrict__ xt, float4* __restrict__ xs)
{
  int q = blockIdx.x * 256 + threadIdx.x;
  int n = q >> 7, dq = q & 127, t = n & (T_ - 1);
  float4 v = x[q];
  xs[q] = v;
  float4 g;
  if (t == 0) {
    g = v;
  } else {
    float4 p = x[q - 128];
    int d0 = dq * 2;
    float c0 = cosp[d0], s0 = sinp[d0], c1 = cosp[d0 + 1], s1 = sinp[d0 + 1];
    g.x = p.x * c0 - p.y * s0;
    g.y = p.x * s0 + p.y * c0;
    g.z = p.z * c1 - p.w * s1;
    g.w = p.z * s1 + p.w * c1;
  }
  xt[q] = g;
}

// ---------------- delays + gate fused: xe + softmax scores ----------------------
__global__ __launch_bounds__(256) void delays_gate_kernel(const float4* __restrict__ xs,
    const float* __restrict__ gains, const float* __restrict__ gw,
    float4* __restrict__ xe, float* __restrict__ scoresT)
{
  int q = blockIdx.x * 256 + threadIdx.x;
  int n = q >> 7, dq = q & 127, t = n & (T_ - 1);
  float4 v = xs[q];
  const int taus[4] = {1, 2, 3, 5};
  int d0 = dq * 2;
  #pragma unroll
  for (int i = 0; i < 4; i++) {
    int tau = taus[i];
    if (t >= tau) {
      float4 p = xs[q - tau * 128];
      float gr0 = gains[(i * D_ + d0) * 2 + 0], gi0 = gains[(i * D_ + d0) * 2 + 1];
      float gr1 = gains[(i * D_ + d0 + 1) * 2 + 0], gi1 = gains[(i * D_ + d0 + 1) * 2 + 1];
      v.x += p.x * gr0 - p.y * gi0;
      v.y += p.x * gi0 + p.y * gr0;
      v.z += p.z * gr1 - p.w * gi1;
      v.w += p.z * gi1 + p.w * gr1;
    }
  }
  xe[q] = v;

  // gate partials: this thread covers k = dq*4 .. dq*4+3
  float p8[8] = {0, 0, 0, 0, 0, 0, 0, 0};
  const float4* gw4 = (const float4*)gw;
  float av[4] = {v.x, v.y, v.z, v.w};
  #pragma unroll
  for (int j = 0; j < 4; j++) {
    float4 w0 = gw4[(dq * 4 + j) * 2];
    float4 w1 = gw4[(dq * 4 + j) * 2 + 1];
    float a = av[j];
    p8[0] = fmaf(a, w0.x, p8[0]);
    p8[1] = fmaf(a, w0.y, p8[1]);
    p8[2] = fmaf(a, w0.z, p8[2]);
    p8[3] = fmaf(a, w0.w, p8[3]);
    p8[4] = fmaf(a, w1.x, p8[4]);
    p8[5] = fmaf(a, w1.y, p8[5]);
    p8[6] = fmaf(a, w1.z, p8[6]);
    p8[7] = fmaf(a, w1.w, p8[7]);
  }
  #pragma unroll
  for (int off = 32; off > 0; off >>= 1)
    #pragma unroll
    for (int e = 0; e < 8; e++) p8[e] += __shfl_down(p8[e], off);
  __shared__ float red[4][8];
  int wv = threadIdx.x >> 6;
  if ((threadIdx.x & 63) == 0)
    #pragma unroll
    for (int e = 0; e < 8; e++) red[wv][e] = p8[e];
  __syncthreads();
  if (threadIdx.x < 2) {
    int tok = blockIdx.x * 2 + threadIdx.x;
    float pe[8], m = -1e30f;
    #pragma unroll
    for (int e = 0; e < 8; e++) {
      pe[e] = red[threadIdx.x * 2][e] + red[threadIdx.x * 2 + 1][e];
      m = fmaxf(m, pe[e]);
    }
    float ssum = 0.f;
    #pragma unroll
    for (int e = 0; e < 8; e++) { pe[e] = expf(pe[e] - m); ssum += pe[e]; }
    float inv = 1.0f / ssum;
    #pragma unroll
    for (int e = 0; e < 8; e++) scoresT[e * NTOK + tok] = pe[e] * inv;
  }
}

// ---------------- exact top-2048 per expert: LDS-hist radix + scan tie-break -----
__global__ __launch_bounds__(1024) void select_kernel(const float* __restrict__ scoresT,
    int* __restrict__ idxl, int* __restrict__ slot_of)
{
  int e = blockIdx.x;
  const float* s = scoresT + (size_t)e * NTOK;
  int tid = threadIdx.x;
  int lane = tid & 63, wv = tid >> 6;   // 16 waves

  // load 16 values into registers: value r=j*4+cc has index n = 4*tid + 4096*j + cc
  float4 f[4];
  #pragma unroll
  for (int j = 0; j < 4; j++) f[j] = ((const float4*)s)[tid + 1024 * j];
  unsigned uv[16];
  #pragma unroll
  for (int j = 0; j < 4; j++) {
    uv[j * 4 + 0] = __float_as_uint(f[j].x);
    uv[j * 4 + 1] = __float_as_uint(f[j].y);
    uv[j * 4 + 2] = __float_as_uint(f[j].z);
    uv[j * 4 + 3] = __float_as_uint(f[j].w);
  }

  __shared__ int hist[16][257];
  __shared__ int histsum[256];
  __shared__ int sfx[2][256];
  __shared__ int wsum[16], wpre[16];
  __shared__ int shB, shK, shTot, scnt;

  unsigned prefix = 0;
  int k = CAP_;
  for (int p = 0; p < 4; ++p) {
    int shift = 24 - 8 * p;
    for (int b = tid; b < 16 * 257; b += 1024) ((int*)hist)[b] = 0;
    __syncthreads();
    #pragma unroll
    for (int r = 0; r < 16; r++) {
      unsigned u = uv[r];
      bool match = (p == 0) || ((u >> (shift + 8)) == prefix);
      if (match) atomicAdd(&hist[wv][(u >> shift) & 255], 1);
    }
    __syncthreads();
    if (tid < 256) {
      int tsum = 0;
      #pragma unroll
      for (int w = 0; w < 16; w++) tsum += hist[w][tid];
      histsum[tid] = tsum;
      sfx[0][tid] = tsum;
    }
    __syncthreads();
    // inclusive suffix sum over 256 buckets (Hillis-Steele, 8 steps)
    int cur = 0;
    #pragma unroll
    for (int d = 1; d < 256; d <<= 1) {
      if (tid < 256)
        sfx[cur ^ 1][tid] = sfx[cur][tid] + ((tid + d < 256) ? sfx[cur][tid + d] : 0);
      __syncthreads();
      cur ^= 1;
    }
    if (tid < 256) {
      int sv = sfx[cur][tid];
      int snext = (tid < 255) ? sfx[cur][tid + 1] : 0;
      if (sv >= k && snext < k) { shB = tid; shK = k - snext; }
    }
    __syncthreads();
    prefix = (prefix << 8) | (unsigned)shB;
    k = shK;
    __syncthreads();
  }
  unsigned thr = prefix;
  int kk = k;   // how many of the tied (== thr) values to take, lowest index first

  // ---- output: take = (u > thr) || (u == thr && index-rank among ties < kk) ----
  if (tid == 0) scnt = 0;
  __syncthreads();
  int jb = 0;   // tie-count base over j blocks (n-major ordering: j, then tid, then cc)
  #pragma unroll
  for (int j = 0; j < 4; j++) {
    int eqf[4], c = 0;
    #pragma unroll
    for (int cc = 0; cc < 4; cc++) {
      eqf[cc] = (uv[j * 4 + cc] == thr) ? 1 : 0;
      c += eqf[cc];
    }
    // wave inclusive scan of per-thread tie counts
    int sc = c;
    #pragma unroll
    for (int d = 1; d < 64; d <<= 1) {
      int tt = __shfl_up(sc, d);
      if (lane >= d) sc += tt;
    }
    if (lane == 63) wsum[wv] = sc;
    __syncthreads();
    if (tid == 0) {
      int a = 0;
      #pragma unroll
      for (int w = 0; w < 16; w++) { int t2 = wsum[w]; wpre[w] = a; a += t2; }
      shTot = a;
    }
    __syncthreads();
    int excl = wpre[wv] + (sc - c);   // exclusive prefix of ties for this thread
    int local = 0;
    int sov[4];
    #pragma unroll
    for (int cc = 0; cc < 4; cc++) {
      unsigned u = uv[j * 4 + cc];
      int n = 4 * tid + 4096 * j + cc;
      bool take = (u > thr) || (eqf[cc] && (jb + excl + local) < kk);
      local += eqf[cc];
      unsigned long long msk = __ballot(take);
      int cntw = __popcll(msk);
      int base = 0;
      if (lane == 0 && cntw) base = atomicAdd(&scnt, cntw);
      base = __shfl(base, 0);
      int slot = base + __popcll(msk & ((1ull << lane) - 1ull));
      int sv = -1;
      if (take) {
        idxl[e * CAP_ + slot] = n;
        sv = slot;
      }
      sov[cc] = sv;
    }
    int4 so;
    so.x = sov[0]; so.y = sov[1]; so.z = sov[2]; so.w = sov[3];
    ((int4*)(slot_of + (size_t)e * NTOK))[tid + 1024 * j] = so;
    jb += shTot;
    __syncthreads();
  }
}

// ------- per-expert fp32 GEMM -> yo (swizzled LDS + register double-buffer) ------
#define GM 128
#define GN 128
#define GKK 32
__device__ __forceinline__ float comp4(const float4 v, int u) {
  return u == 0 ? v.x : u == 1 ? v.y : u == 2 ? v.z : v.w;
}
__global__ __launch_bounds__(256) void gemm_kernel(const float* __restrict__ xe,
    const float* __restrict__ ew, const int* __restrict__ idxl, float* __restrict__ yo)
{
  int bid0 = blockIdx.x;
  // XCD swizzle: 512 blocks / 8 XCDs -> each XCD gets one expert (A panel 4MB, L2-fit)
  int bid = (bid0 & 7) * 64 + (bid0 >> 3);
  int e = bid >> 6, rem = bid & 63, mt = rem >> 2, nt = rem & 3;
  __shared__ float4 As4[GM * 8];      // slot = row*8 + (kq ^ (row>>3 & 7))
  __shared__ float4 Bs4[GKK * 32];    // slot = k*32 + c   (c = col/4)
  int tid = threadIdx.x;
  int tx = tid & 15, ty = tid >> 4;
  const float* We = ew + (size_t)e * TWOD * TWOD + nt * GN;

  // staging addresses (pointer-increment form; slot layout identical to R3)
  const float* aptr[4];
  const float* bptr[4];
  int aslot[4], bslot[4];
  #pragma unroll
  for (int l = 0; l < 4; l++) {
    int id = tid + l * 256;
    int row = id >> 3, kq = id & 7;
    int tok = idxl[e * CAP_ + mt * GM + row];
    aptr[l] = xe + (size_t)tok * TWOD + kq * 4;
    aslot[l] = row * 8 + (kq ^ ((row >> 3) & 7));
    int kkk = id >> 5, cc = id & 31;
    bptr[l] = We + (size_t)kkk * TWOD + cc * 4;
    bslot[l] = kkk * 32 + cc;
  }
  float4 pa[4], pb[4];
  #pragma unroll
  for (int l = 0; l < 4; l++) { pa[l] = *(const float4*)aptr[l]; pb[l] = *(const float4*)bptr[l]; }
  #pragma unroll
  for (int l = 0; l < 4; l++) { As4[aslot[l]] = pa[l]; Bs4[bslot[l]] = pb[l]; }
  __syncthreads();

  float acc[8][8] = {};   // rows ty*8+i ; cols: jj<4 -> tx*4+jj, jj>=4 -> 64+tx*4+jj-4

  for (int kb = GKK; kb <= TWOD; kb += GKK) {
    bool has_next = (kb < TWOD);
    if (has_next) {
      // issue next tile's global loads; results consumed only after the barrier
      #pragma unroll
      for (int l = 0; l < 4; l++) {
        pa[l] = *(const float4*)(aptr[l] + kb);
        pb[l] = *(const float4*)(bptr[l] + (size_t)kb * TWOD);
      }
    }
    #pragma unroll
    for (int k4 = 0; k4 < GKK; k4 += 4) {
      int kq = k4 >> 2;
      float4 a4[8], b4[8];
      #pragma unroll
      for (int i = 0; i < 8; i++) a4[i] = As4[(ty * 8 + i) * 8 + (kq ^ (ty & 7))];
      #pragma unroll
      for (int u = 0; u < 4; u++) {
        b4[2 * u]     = Bs4[(k4 + u) * 32 + tx];
        b4[2 * u + 1] = Bs4[(k4 + u) * 32 + 16 + tx];
      }
      #pragma unroll
      for (int u = 0; u < 4; u++) {
        float av[8], bv[8];
        #pragma unroll
        for (int i = 0; i < 8; i++) av[i] = comp4(a4[i], u);
        bv[0] = b4[2*u].x; bv[1] = b4[2*u].y; bv[2] = b4[2*u].z; bv[3] = b4[2*u].w;
        bv[4] = b4[2*u+1].x; bv[5] = b4[2*u+1].y; bv[6] = b4[2*u+1].z; bv[7] = b4[2*u+1].w;
        #pragma unroll
        for (int i = 0; i < 8; i++)
          #pragma unroll
          for (int jj = 0; jj < 8; jj++)
            acc[i][jj] = fmaf(av[i], bv[jj], acc[i][jj]);
      }
    }
    __syncthreads();
    if (has_next) {
      #pragma unroll
      for (int l = 0; l < 4; l++) { As4[aslot[l]] = pa[l]; Bs4[bslot[l]] = pb[l]; }
      __syncthreads();
    }
  }
  #pragma unroll
  for (int i = 0; i < 8; i++) {
    float* dst = yo + (size_t)(e * CAP_ + mt * GM + ty * 8 + i) * TWOD + nt * GN + tx * 4;
    float4 o0 = {acc[i][0], acc[i][1], acc[i][2], acc[i][3]};
    float4 o1 = {acc[i][4], acc[i][5], acc[i][6], acc[i][7]};
    *(float4*)dst = o0;
    *(float4*)(dst + 64) = o1;
  }
}

// ---------------- combine (gather yo) + state update -----------------------------
__global__ __launch_bounds__(256) void combine_update_kernel(const float4* __restrict__ yo,
    const float* __restrict__ scoresT, const int* __restrict__ slot_of,
    const float4* __restrict__ xt, float4* __restrict__ xs,
    float4* __restrict__ pred, int* __restrict__ counts, float lr, int write_pred)
{
  int q = blockIdx.x * 256 + threadIdx.x;
  int n = q >> 7, dq = q & 127;
  float4 p = {0, 0, 0, 0};
  int cnt = 0;
  #pragma unroll
  for (int e = 0; e < E_; e++) {
    int sl = slot_of[e * NTOK + n];
    if (sl >= 0) {
      float val = scoresT[e * NTOK + n];
      float4 y = yo[(size_t)(e * CAP_ + sl) * 128 + dq];
      p.x = fmaf(val, y.x, p.x);
      p.y = fmaf(val, y.y, p.y);
      p.z = fmaf(val, y.z, p.z);
      p.w = fmaf(val, y.w, p.w);
      cnt++;
    }
  }
  float4 t = xt[q], s = xs[q];
  s.x += lr * fminf(fmaxf(t.x - p.x, -10.f), 10.f);
  s.y += lr * fminf(fmaxf(t.y - p.y, -10.f), 10.f);
  s.z += lr * fminf(fmaxf(t.z - p.z, -10.f), 10.f);
  s.w += lr * fminf(fmaxf(t.w - p.w, -10.f), 10.f);
  xs[q] = s;
  if (write_pred) {
    pred[q] = p;
    if (dq == 0) counts[n] = cnt;
  }
}

// ---------------- combine (gather yo) + final out + res partial -------------------
__global__ __launch_bounds__(256) void combine_final_kernel(const float4* __restrict__ yo,
    const float* __restrict__ scoresT, const int* __restrict__ slot_of,
    const float4* __restrict__ xt, const float4* __restrict__ xs,
    float4* __restrict__ out, float* __restrict__ racc)
{
  int q = blockIdx.x * 256 + threadIdx.x;
  int n = q >> 7, dq = q & 127;
  float4 p = {0, 0, 0, 0};
  #pragma unroll
  for (int e = 0; e < E_; e++) {
    int sl = slot_of[e * NTOK + n];
    if (sl >= 0) {
      float val = scoresT[e * NTOK + n];
      float4 y = yo[(size_t)(e * CAP_ + sl) * 128 + dq];
      p.x = fmaf(val, y.x, p.x);
      p.y = fmaf(val, y.y, p.y);
      p.z = fmaf(val, y.z, p.z);
      p.w = fmaf(val, y.w, p.w);
    }
  }
  float4 t = xt[q], s = xs[q];
  float dr0 = t.x - p.x, di0 = t.y - p.y, dr1 = t.z - p.z, di1 = t.w - p.w;
  float4 o = {s.x + 0.5f * dr0, s.y + 0.5f * di0, s.z + 0.5f * dr1, s.w + 0.5f * di1};
  out[q] = o;
  float lsum = sqrtf(dr0 * dr0 + di0 * di0) + sqrtf(dr1 * dr1 + di1 * di1);
  __shared__ float red[256];
  red[threadIdx.x] = lsum;
  __syncthreads();
  for (int off = 128; off > 0; off >>= 1) {
    if (threadIdx.x < off) red[threadIdx.x] += red[threadIdx.x + off];
    __syncthreads();
  }
  if (threadIdx.x == 0) atomicAdd(racc, red[0]);
}

// ---------------- x_states = tanh(pred / max(counts,1) + bias) -------------------
__global__ __launch_bounds__(256) void activate_kernel(const float4* __restrict__ pred,
    const int* __restrict__ counts, const float4* __restrict__ bias, float4* __restrict__ xs)
{
  int q = blockIdx.x * 256 + threadIdx.x;
  int n = q >> 7;
  float denom = fmaxf((float)counts[n], 1.0f);
  float4 p = pred[q];
  float4 b = bias[q & 127];
  float4 r;
  r.x = tanhf(p.x / denom + b.x);
  r.y = tanhf(p.y / denom + b.y);
  r.z = tanhf(p.z / denom + b.z);
  r.w = tanhf(p.w / denom + b.w);
  xs[q] = r;
}

__global__ void finish_kernel(const float* __restrict__ racc, float* __restrict__ dst)
{
  if (threadIdx.x == 0) dst[0] = racc[0] / 4194304.0f;
}

// ---------------- host launch ----------------------------------------------------
extern "C" void kernel_launch(void* const* d_in, const int* in_sizes, int n_in,
                              void* d_out, int out_size, void* d_ws, size_t ws_size,
                              hipStream_t stream)
{
  const float* x     = (const float*)d_in[0];
  const float* gains = (const float*)d_in[1];
  const float* cosp  = (const float*)d_in[2];
  const float* sinp  = (const float*)d_in[3];
  const float* gw    = (const float*)d_in[4];
  const float* ew    = (const float*)d_in[5];
  const float* bias  = (const float*)d_in[6];
  float* out = (float*)d_out;

  char* w = (char*)d_ws;
  size_t off = 0;
  auto alloc = [&](size_t bytes) -> void* {
    void* p = w + off;
    off += (bytes + 255) & ~(size_t)255;
    return p;
  };
  float* xt      = (float*)alloc((size_t)NTOK * TWOD * 4);
  float* xs      = (float*)alloc((size_t)NTOK * TWOD * 4);
  float* xe      = (float*)alloc((size_t)NTOK * TWOD * 4);
  float* pred    = (float*)alloc((size_t)NTOK * TWOD * 4);
  float* yo      = (float*)alloc((size_t)E_ * CAP_ * TWOD * 4);
  float* scoresT = (float*)alloc((size_t)E_ * NTOK * 4);
  int*   idxl    = (int*)  alloc((size_t)E_ * CAP_ * 4);
  int*   slot_of = (int*)  alloc((size_t)E_ * NTOK * 4);
  int*   counts  = (int*)  alloc((size_t)NTOK * 4);
  float* racc    = (float*)alloc(256);

  const int eb = NQ / 256;  // 8192

  init_kernel<<<eb, 256, 0, stream>>>((const float4*)x, cosp, sinp, (float4*)xt, (float4*)xs);

  double lr = 0.5;
  for (int it = 0; it < 9; ++it) {
    if (it == 8)
      activate_kernel<<<eb, 256, 0, stream>>>((const float4*)pred, counts,
                                              (const float4*)bias, (float4*)xs);
    delays_gate_kernel<<<eb, 256, 0, stream>>>((const float4*)xs, gains, gw,
                                               (float4*)xe, scoresT);
    select_kernel<<<E_, 1024, 0, stream>>>(scoresT, idxl, slot_of);
    gemm_kernel<<<512, 256, 0, stream>>>(xe, ew, idxl, yo);
    if (it < 8) {
      combine_update_kernel<<<eb, 256, 0, stream>>>((const float4*)yo, scoresT, slot_of,
          (const float4*)xt, (float4*)xs, (float4*)pred, counts, (float)lr, it == 7 ? 1 : 0);
      lr *= 0.85;
    } else {
      hipMemsetAsync(racc, 0, 4, stream);
      combine_final_kernel<<<eb, 256, 0, stream>>>((const float4*)yo, scoresT, slot_of,
          (const float4*)xt, (const float4*)xs, (float4*)out, racc);
    }
  }
  finish_kernel<<<1, 64, 0, stream>>>(racc, out + (size_t)NTOK * TWOD);
}

// Round 6
// 2102.722 us; speedup vs baseline: 2.5557x; 2.5557x over previous
//
#include <hip/hip_runtime.h>

#define T_    8192
#define D_    256
#define E_    8
#define TWOD  512
#define NTOK  16384
#define CAP_  2048
#define NQ    (NTOK * 128)   // float4 count of an (N, 512) fp32 array

// ---------------- init: x_states = x, x_target = phase_targets(x) ----------------
__global__ __launch_bounds__(256) void init_kernel(const float4* __restrict__ x,
    const float* __restrict__ cosp, const float* __restrict__ sinp,
    float4* __restrict__ xt, float4* __restrict__ xs)
{
  int q = blockIdx.x * 256 + threadIdx.x;
  int n = q >> 7, dq = q & 127, t = n & (T_ - 1);
  float4 v = x[q];
  xs[q] = v;
  float4 g;
  if (t == 0) {
    g = v;
  } else {
    float4 p = x[q - 128];
    int d0 = dq * 2;
    float c0 = cosp[d0], s0 = sinp[d0], c1 = cosp[d0 + 1], s1 = sinp[d0 + 1];
    g.x = p.x * c0 - p.y * s0;
    g.y = p.x * s0 + p.y * c0;
    g.z = p.z * c1 - p.w * s1;
    g.w = p.z * s1 + p.w * c1;
  }
  xt[q] = g;
}

// ---------------- delays + gate fused: xe + softmax scores ----------------------
__global__ __launch_bounds__(256) void delays_gate_kernel(const float4* __restrict__ xs,
    const float* __restrict__ gains, const float* __restrict__ gw,
    float4* __restrict__ xe, float* __restrict__ scoresT)
{
  int q = blockIdx.x * 256 + threadIdx.x;
  int n = q >> 7, dq = q & 127, t = n & (T_ - 1);
  float4 v = xs[q];
  const int taus[4] = {1, 2, 3, 5};
  int d0 = dq * 2;
  #pragma unroll
  for (int i = 0; i < 4; i++) {
    int tau = taus[i];
    if (t >= tau) {
      float4 p = xs[q - tau * 128];
      float gr0 = gains[(i * D_ + d0) * 2 + 0], gi0 = gains[(i * D_ + d0) * 2 + 1];
      float gr1 = gains[(i * D_ + d0 + 1) * 2 + 0], gi1 = gains[(i * D_ + d0 + 1) * 2 + 1];
      v.x += p.x * gr0 - p.y * gi0;
      v.y += p.x * gi0 + p.y * gr0;
      v.z += p.z * gr1 - p.w * gi1;
      v.w += p.z * gi1 + p.w * gr1;
    }
  }
  xe[q] = v;

  // gate partials: this thread covers k = dq*4 .. dq*4+3
  float p8[8] = {0, 0, 0, 0, 0, 0, 0, 0};
  const float4* gw4 = (const float4*)gw;
  float av[4] = {v.x, v.y, v.z, v.w};
  #pragma unroll
  for (int j = 0; j < 4; j++) {
    float4 w0 = gw4[(dq * 4 + j) * 2];
    float4 w1 = gw4[(dq * 4 + j) * 2 + 1];
    float a = av[j];
    p8[0] = fmaf(a, w0.x, p8[0]);
    p8[1] = fmaf(a, w0.y, p8[1]);
    p8[2] = fmaf(a, w0.z, p8[2]);
    p8[3] = fmaf(a, w0.w, p8[3]);
    p8[4] = fmaf(a, w1.x, p8[4]);
    p8[5] = fmaf(a, w1.y, p8[5]);
    p8[6] = fmaf(a, w1.z, p8[6]);
    p8[7] = fmaf(a, w1.w, p8[7]);
  }
  #pragma unroll
  for (int off = 32; off > 0; off >>= 1)
    #pragma unroll
    for (int e = 0; e < 8; e++) p8[e] += __shfl_down(p8[e], off);
  __shared__ float red[4][8];
  int wv = threadIdx.x >> 6;
  if ((threadIdx.x & 63) == 0)
    #pragma unroll
    for (int e = 0; e < 8; e++) red[wv][e] = p8[e];
  __syncthreads();
  if (threadIdx.x < 2) {
    int tok = blockIdx.x * 2 + threadIdx.x;
    float pe[8], m = -1e30f;
    #pragma unroll
    for (int e = 0; e < 8; e++) {
      pe[e] = red[threadIdx.x * 2][e] + red[threadIdx.x * 2 + 1][e];
      m = fmaxf(m, pe[e]);
    }
    float ssum = 0.f;
    #pragma unroll
    for (int e = 0; e < 8; e++) { pe[e] = expf(pe[e] - m); ssum += pe[e]; }
    float inv = 1.0f / ssum;
    #pragma unroll
    for (int e = 0; e < 8; e++) scoresT[e * NTOK + tok] = pe[e] * inv;
  }
}

// ---------------- exact top-2048 per expert: LDS-hist radix + scan tie-break -----
__global__ __launch_bounds__(1024) void select_kernel(const float* __restrict__ scoresT,
    int* __restrict__ idxl, int* __restrict__ slot_of)
{
  int e = blockIdx.x;
  const float* s = scoresT + (size_t)e * NTOK;
  int tid = threadIdx.x;
  int lane = tid & 63, wv = tid >> 6;   // 16 waves

  // load 16 values into registers: value r=j*4+cc has index n = 4*tid + 4096*j + cc
  float4 f[4];
  #pragma unroll
  for (int j = 0; j < 4; j++) f[j] = ((const float4*)s)[tid + 1024 * j];
  unsigned uv[16];
  #pragma unroll
  for (int j = 0; j < 4; j++) {
    uv[j * 4 + 0] = __float_as_uint(f[j].x);
    uv[j * 4 + 1] = __float_as_uint(f[j].y);
    uv[j * 4 + 2] = __float_as_uint(f[j].z);
    uv[j * 4 + 3] = __float_as_uint(f[j].w);
  }

  __shared__ int hist[16][257];
  __shared__ int histsum[256];
  __shared__ int sfx[2][256];
  __shared__ int wsum[16], wpre[16];
  __shared__ int shB, shK, shTot, scnt;

  unsigned prefix = 0;
  int k = CAP_;
  for (int p = 0; p < 4; ++p) {
    int shift = 24 - 8 * p;
    for (int b = tid; b < 16 * 257; b += 1024) ((int*)hist)[b] = 0;
    __syncthreads();
    #pragma unroll
    for (int r = 0; r < 16; r++) {
      unsigned u = uv[r];
      bool match = (p == 0) || ((u >> (shift + 8)) == prefix);
      if (match) atomicAdd(&hist[wv][(u >> shift) & 255], 1);
    }
    __syncthreads();
    if (tid < 256) {
      int tsum = 0;
      #pragma unroll
      for (int w = 0; w < 16; w++) tsum += hist[w][tid];
      histsum[tid] = tsum;
      sfx[0][tid] = tsum;
    }
    __syncthreads();
    // inclusive suffix sum over 256 buckets (Hillis-Steele, 8 steps)
    int cur = 0;
    #pragma unroll
    for (int d = 1; d < 256; d <<= 1) {
      if (tid < 256)
        sfx[cur ^ 1][tid] = sfx[cur][tid] + ((tid + d < 256) ? sfx[cur][tid + d] : 0);
      __syncthreads();
      cur ^= 1;
    }
    if (tid < 256) {
      int sv = sfx[cur][tid];
      int snext = (tid < 255) ? sfx[cur][tid + 1] : 0;
      if (sv >= k && snext < k) { shB = tid; shK = k - snext; }
    }
    __syncthreads();
    prefix = (prefix << 8) | (unsigned)shB;
    k = shK;
    __syncthreads();
  }
  unsigned thr = prefix;
  int kk = k;   // how many of the tied (== thr) values to take, lowest index first

  // ---- output: take = (u > thr) || (u == thr && index-rank among ties < kk) ----
  if (tid == 0) scnt = 0;
  __syncthreads();
  int jb = 0;   // tie-count base over j blocks (n-major ordering: j, then tid, then cc)
  #pragma unroll
  for (int j = 0; j < 4; j++) {
    int eqf[4], c = 0;
    #pragma unroll
    for (int cc = 0; cc < 4; cc++) {
      eqf[cc] = (uv[j * 4 + cc] == thr) ? 1 : 0;
      c += eqf[cc];
    }
    // wave inclusive scan of per-thread tie counts
    int sc = c;
    #pragma unroll
    for (int d = 1; d < 64; d <<= 1) {
      int tt = __shfl_up(sc, d);
      if (lane >= d) sc += tt;
    }
    if (lane == 63) wsum[wv] = sc;
    __syncthreads();
    if (tid == 0) {
      int a = 0;
      #pragma unroll
      for (int w = 0; w < 16; w++) { int t2 = wsum[w]; wpre[w] = a; a += t2; }
      shTot = a;
    }
    __syncthreads();
    int excl = wpre[wv] + (sc - c);   // exclusive prefix of ties for this thread
    int local = 0;
    int sov[4];
    #pragma unroll
    for (int cc = 0; cc < 4; cc++) {
      unsigned u = uv[j * 4 + cc];
      int n = 4 * tid + 4096 * j + cc;
      bool take = (u > thr) || (eqf[cc] && (jb + excl + local) < kk);
      local += eqf[cc];
      unsigned long long msk = __ballot(take);
      int cntw = __popcll(msk);
      int base = 0;
      if (lane == 0 && cntw) base = atomicAdd(&scnt, cntw);
      base = __shfl(base, 0);
      int slot = base + __popcll(msk & ((1ull << lane) - 1ull));
      int sv = -1;
      if (take) {
        idxl[e * CAP_ + slot] = n;
        sv = slot;
      }
      sov[cc] = sv;
    }
    int4 so;
    so.x = sov[0]; so.y = sov[1]; so.z = sov[2]; so.w = sov[3];
    ((int4*)(slot_of + (size_t)e * NTOK))[tid + 1024 * j] = so;
    jb += shTot;
    __syncthreads();
  }
}

// ------- per-expert fp32 GEMM -> yo: global_load_lds staging + LDS dbuf ----------
// A slot s in [0,1024): row = s>>3, kqs = s&7, holds A[row][ (kqs ^ (row>>3 & 7))*4 ..+4 )
// B slot s in [0,1024): kkk = s>>5, cc = s&31, holds B[kkk][cc*4 ..+4)
#define GM 128
#define GN 128
#define GKK 32
__device__ __forceinline__ float comp4(const float4 v, int u) {
  return u == 0 ? v.x : u == 1 ? v.y : u == 2 ? v.z : v.w;
}
__device__ __forceinline__ void gl_lds16(const void* g, void* l) {
  __builtin_amdgcn_global_load_lds(
      (const __attribute__((address_space(1))) unsigned int*)g,
      (__attribute__((address_space(3))) unsigned int*)l, 16, 0, 0);
}
__global__ __launch_bounds__(256) void gemm_kernel(const float* __restrict__ xe,
    const float* __restrict__ ew, const int* __restrict__ idxl, float* __restrict__ yo)
{
  int bid0 = blockIdx.x;
  // XCD swizzle: 512 blocks / 8 XCDs -> each XCD gets one expert (A panel 4MB, L2-fit)
  int bid = (bid0 & 7) * 64 + (bid0 >> 3);
  int e = bid >> 6, rem = bid & 63, mt = rem >> 2, nt = rem & 3;
  __shared__ float4 AB[2 * 2048];   // buf b: A at b*2048, B at b*2048+1024 (64 KB total)
  int tid = threadIdx.x;
  int tx = tid & 15, ty = tid >> 4;
  const float* We = ew + (size_t)e * TWOD * TWOD + nt * GN;

  // per-lane pre-swizzled global source pointers; LDS dest is linear (lane-ordered)
  const float* aptr0[4];
  const float* bptr0[4];
  #pragma unroll
  for (int l = 0; l < 4; l++) {
    int slot = l * 256 + tid;
    int row = slot >> 3, kqs = slot & 7;
    int kq = kqs ^ ((row >> 3) & 7);
    int tok = idxl[e * CAP_ + mt * GM + row];
    aptr0[l] = xe + (size_t)tok * TWOD + kq * 4;
    int kkk = slot >> 5, cc = slot & 31;
    bptr0[l] = We + (size_t)kkk * TWOD + cc * 4;
  }
  int wbase = tid & 192;   // wave-uniform: (tid>>6)*64

  // stage tile at k-offset kb (floats) into buffer `buf`
  auto stage = [&](int buf, int kb) {
    float4* dA = AB + buf * 2048 + wbase;
    float4* dB = dA + 1024;
    #pragma unroll
    for (int l = 0; l < 4; l++) {
      gl_lds16(aptr0[l] + kb, (void*)(dA + l * 256));
      gl_lds16(bptr0[l] + (size_t)kb * TWOD, (void*)(dB + l * 256));
    }
  };

  stage(0, 0);
  __syncthreads();   // drains vmcnt -> tile 0 resident

  float acc[8][8] = {};   // rows ty*8+i ; cols: jj<4 -> tx*4+jj, jj>=4 -> 64+tx*4+jj-4
  int cur = 0;

  for (int kb = GKK; kb <= TWOD; kb += GKK) {
    if (kb < TWOD) stage(cur ^ 1, kb);   // in-flight across the compute phase
    const float4* As4 = AB + cur * 2048;
    const float4* Bs4 = As4 + 1024;
    #pragma unroll
    for (int k4 = 0; k4 < GKK; k4 += 4) {
      int kq = k4 >> 2;
      float4 a4[8], b4[8];
      #pragma unroll
      for (int i = 0; i < 8; i++) a4[i] = As4[(ty * 8 + i) * 8 + (kq ^ (ty & 7))];
      #pragma unroll
      for (int u = 0; u < 4; u++) {
        b4[2 * u]     = Bs4[(k4 + u) * 32 + tx];
        b4[2 * u + 1] = Bs4[(k4 + u) * 32 + 16 + tx];
      }
      #pragma unroll
      for (int u = 0; u < 4; u++) {
        float av[8], bv[8];
        #pragma unroll
        for (int i = 0; i < 8; i++) av[i] = comp4(a4[i], u);
        bv[0] = b4[2*u].x; bv[1] = b4[2*u].y; bv[2] = b4[2*u].z; bv[3] = b4[2*u].w;
        bv[4] = b4[2*u+1].x; bv[5] = b4[2*u+1].y; bv[6] = b4[2*u+1].z; bv[7] = b4[2*u+1].w;
        #pragma unroll
        for (int i = 0; i < 8; i++)
          #pragma unroll
          for (int jj = 0; jj < 8; jj++)
            acc[i][jj] = fmaf(av[i], bv[jj], acc[i][jj]);
      }
    }
    __syncthreads();   // vmcnt drain lands AFTER ~4096 cy of FMA; next tile ready
    cur ^= 1;
  }

  #pragma unroll
  for (int i = 0; i < 8; i++) {
    float* dst = yo + (size_t)(e * CAP_ + mt * GM + ty * 8 + i) * TWOD + nt * GN + tx * 4;
    float4 o0 = {acc[i][0], acc[i][1], acc[i][2], acc[i][3]};
    float4 o1 = {acc[i][4], acc[i][5], acc[i][6], acc[i][7]};
    *(float4*)dst = o0;
    *(float4*)(dst + 64) = o1;
  }
}

// ---------------- combine (gather yo) + state update -----------------------------
__global__ __launch_bounds__(256) void combine_update_kernel(const float4* __restrict__ yo,
    const float* __restrict__ scoresT, const int* __restrict__ slot_of,
    const float4* __restrict__ xt, float4* __restrict__ xs,
    float4* __restrict__ pred, int* __restrict__ counts, float lr, int write_pred)
{
  int q = blockIdx.x * 256 + threadIdx.x;
  int n = q >> 7, dq = q & 127;
  float4 p = {0, 0, 0, 0};
  int cnt = 0;
  #pragma unroll
  for (int e = 0; e < E_; e++) {
    int sl = slot_of[e * NTOK + n];
    if (sl >= 0) {
      float val = scoresT[e * NTOK + n];
      float4 y = yo[(size_t)(e * CAP_ + sl) * 128 + dq];
      p.x = fmaf(val, y.x, p.x);
      p.y = fmaf(val, y.y, p.y);
      p.z = fmaf(val, y.z, p.z);
      p.w = fmaf(val, y.w, p.w);
      cnt++;
    }
  }
  float4 t = xt[q], s = xs[q];
  s.x += lr * fminf(fmaxf(t.x - p.x, -10.f), 10.f);
  s.y += lr * fminf(fmaxf(t.y - p.y, -10.f), 10.f);
  s.z += lr * fminf(fmaxf(t.z - p.z, -10.f), 10.f);
  s.w += lr * fminf(fmaxf(t.w - p.w, -10.f), 10.f);
  xs[q] = s;
  if (write_pred) {
    pred[q] = p;
    if (dq == 0) counts[n] = cnt;
  }
}

// ---------------- combine (gather yo) + final out + res partial -------------------
__global__ __launch_bounds__(256) void combine_final_kernel(const float4* __restrict__ yo,
    const float* __restrict__ scoresT, const int* __restrict__ slot_of,
    const float4* __restrict__ xt, const float4* __restrict__ xs,
    float4* __restrict__ out, float* __restrict__ racc)
{
  int q = blockIdx.x * 256 + threadIdx.x;
  int n = q >> 7, dq = q & 127;
  float4 p = {0, 0, 0, 0};
  #pragma unroll
  for (int e = 0; e < E_; e++) {
    int sl = slot_of[e * NTOK + n];
    if (sl >= 0) {
      float val = scoresT[e * NTOK + n];
      float4 y = yo[(size_t)(e * CAP_ + sl) * 128 + dq];
      p.x = fmaf(val, y.x, p.x);
      p.y = fmaf(val, y.y, p.y);
      p.z = fmaf(val, y.z, p.z);
      p.w = fmaf(val, y.w, p.w);
    }
  }
  float4 t = xt[q], s = xs[q];
  float dr0 = t.x - p.x, di0 = t.y - p.y, dr1 = t.z - p.z, di1 = t.w - p.w;
  float4 o = {s.x + 0.5f * dr0, s.y + 0.5f * di0, s.z + 0.5f * dr1, s.w + 0.5f * di1};
  out[q] = o;
  float lsum = sqrtf(dr0 * dr0 + di0 * di0) + sqrtf(dr1 * dr1 + di1 * di1);
  __shared__ float red[256];
  red[threadIdx.x] = lsum;
  __syncthreads();
  for (int off = 128; off > 0; off >>= 1) {
    if (threadIdx.x < off) red[threadIdx.x] += red[threadIdx.x + off];
    __syncthreads();
  }
  if (threadIdx.x == 0) atomicAdd(racc, red[0]);
}

// ---------------- x_states = tanh(pred / max(counts,1) + bias) -------------------
__global__ __launch_bounds__(256) void activate_kernel(const float4* __restrict__ pred,
    const int* __restrict__ counts, const float4* __restrict__ bias, float4* __restrict__ xs)
{
  int q = blockIdx.x * 256 + threadIdx.x;
  int n = q >> 7;
  float denom = fmaxf((float)counts[n], 1.0f);
  float4 p = pred[q];
  float4 b = bias[q & 127];
  float4 r;
  r.x = tanhf(p.x / denom + b.x);
  r.y = tanhf(p.y / denom + b.y);
  r.z = tanhf(p.z / denom + b.z);
  r.w = tanhf(p.w / denom + b.w);
  xs[q] = r;
}

__global__ void finish_kernel(const float* __restrict__ racc, float* __restrict__ dst)
{
  if (threadIdx.x == 0) dst[0] = racc[0] / 4194304.0f;
}

// ---------------- host launch ----------------------------------------------------
extern "C" void kernel_launch(void* const* d_in, const int* in_sizes, int n_in,
                              void* d_out, int out_size, void* d_ws, size_t ws_size,
                              hipStream_t stream)
{
  const float* x     = (const float*)d_in[0];
  const float* gains = (const float*)d_in[1];
  const float* cosp  = (const float*)d_in[2];
  const float* sinp  = (const float*)d_in[3];
  const float* gw    = (const float*)d_in[4];
  const float* ew    = (const float*)d_in[5];
  const float* bias  = (const float*)d_in[6];
  float* out = (float*)d_out;

  char* w = (char*)d_ws;
  size_t off = 0;
  auto alloc = [&](size_t bytes) -> void* {
    void* p = w + off;
    off += (bytes + 255) & ~(size_t)255;
    return p;
  };
  float* xt      = (float*)alloc((size_t)NTOK * TWOD * 4);
  float* xs      = (float*)alloc((size_t)NTOK * TWOD * 4);
  float* xe      = (float*)alloc((size_t)NTOK * TWOD * 4);
  float* pred    = (float*)alloc((size_t)NTOK * TWOD * 4);
  float* yo      = (float*)alloc((size_t)E_ * CAP_ * TWOD * 4);
  float* scoresT = (float*)alloc((size_t)E_ * NTOK * 4);
  int*   idxl    = (int*)  alloc((size_t)E_ * CAP_ * 4);
  int*   slot_of = (int*)  alloc((size_t)E_ * NTOK * 4);
  int*   counts  = (int*)  alloc((size_t)NTOK * 4);
  float* racc    = (float*)alloc(256);

  const int eb = NQ / 256;  // 8192

  init_kernel<<<eb, 256, 0, stream>>>((const float4*)x, cosp, sinp, (float4*)xt, (float4*)xs);

  double lr = 0.5;
  for (int it = 0; it < 9; ++it) {
    if (it == 8)
      activate_kernel<<<eb, 256, 0, stream>>>((const float4*)pred, counts,
                                              (const float4*)bias, (float4*)xs);
    delays_gate_kernel<<<eb, 256, 0, stream>>>((const float4*)xs, gains, gw,
                                               (float4*)xe, scoresT);
    select_kernel<<<E_, 1024, 0, stream>>>(scoresT, idxl, slot_of);
    gemm_kernel<<<512, 256, 0, stream>>>(xe, ew, idxl, yo);
    if (it < 8) {
      combine_update_kernel<<<eb, 256, 0, stream>>>((const float4*)yo, scoresT, slot_of,
          (const float4*)xt, (float4*)xs, (float4*)pred, counts, (float)lr, it == 7 ? 1 : 0);
      lr *= 0.85;
    } else {
      hipMemsetAsync(racc, 0, 4, stream);
      combine_final_kernel<<<eb, 256, 0, stream>>>((const float4*)yo, scoresT, slot_of,
          (const float4*)xt, (const float4*)xs, (float4*)out, racc);
    }
  }
  finish_kernel<<<1, 64, 0, stream>>>(racc, out + (size_t)NTOK * TWOD);
}

// Round 7
// 1961.484 us; speedup vs baseline: 2.7397x; 1.0720x over previous
//
#include <hip/hip_runtime.h>

#define T_    8192
#define D_    256
#define E_    8
#define TWOD  512
#define NTOK  16384
#define CAP_  2048
#define NQ    (NTOK * 128)   // float4 count of an (N, 512) fp32 array

// ---------------- init: x_states = x, x_target = phase_targets(x) ----------------
__global__ __launch_bounds__(256) void init_kernel(const float4* __restrict__ x,
    const float* __restrict__ cosp, const float* __restrict__ sinp,
    float4* __restrict__ xt, float4* __restrict__ xs)
{
  int q = blockIdx.x * 256 + threadIdx.x;
  int n = q >> 7, dq = q & 127, t = n & (T_ - 1);
  float4 v = x[q];
  xs[q] = v;
  float4 g;
  if (t == 0) {
    g = v;
  } else {
    float4 p = x[q - 128];
    int d0 = dq * 2;
    float c0 = cosp[d0], s0 = sinp[d0], c1 = cosp[d0 + 1], s1 = sinp[d0 + 1];
    g.x = p.x * c0 - p.y * s0;
    g.y = p.x * s0 + p.y * c0;
    g.z = p.z * c1 - p.w * s1;
    g.w = p.z * s1 + p.w * c1;
  }
  xt[q] = g;
}

// ---------------- delays + gate fused: xe + softmax scores ----------------------
__global__ __launch_bounds__(256) void delays_gate_kernel(const float4* __restrict__ xs,
    const float* __restrict__ gains, const float* __restrict__ gw,
    float4* __restrict__ xe, float* __restrict__ scoresT)
{
  int q = blockIdx.x * 256 + threadIdx.x;
  int n = q >> 7, dq = q & 127, t = n & (T_ - 1);
  float4 v = xs[q];
  const int taus[4] = {1, 2, 3, 5};
  int d0 = dq * 2;
  #pragma unroll
  for (int i = 0; i < 4; i++) {
    int tau = taus[i];
    if (t >= tau) {
      float4 p = xs[q - tau * 128];
      float gr0 = gains[(i * D_ + d0) * 2 + 0], gi0 = gains[(i * D_ + d0) * 2 + 1];
      float gr1 = gains[(i * D_ + d0 + 1) * 2 + 0], gi1 = gains[(i * D_ + d0 + 1) * 2 + 1];
      v.x += p.x * gr0 - p.y * gi0;
      v.y += p.x * gi0 + p.y * gr0;
      v.z += p.z * gr1 - p.w * gi1;
      v.w += p.z * gi1 + p.w * gr1;
    }
  }
  xe[q] = v;

  // gate partials: this thread covers k = dq*4 .. dq*4+3
  float p8[8] = {0, 0, 0, 0, 0, 0, 0, 0};
  const float4* gw4 = (const float4*)gw;
  float av[4] = {v.x, v.y, v.z, v.w};
  #pragma unroll
  for (int j = 0; j < 4; j++) {
    float4 w0 = gw4[(dq * 4 + j) * 2];
    float4 w1 = gw4[(dq * 4 + j) * 2 + 1];
    float a = av[j];
    p8[0] = fmaf(a, w0.x, p8[0]);
    p8[1] = fmaf(a, w0.y, p8[1]);
    p8[2] = fmaf(a, w0.z, p8[2]);
    p8[3] = fmaf(a, w0.w, p8[3]);
    p8[4] = fmaf(a, w1.x, p8[4]);
    p8[5] = fmaf(a, w1.y, p8[5]);
    p8[6] = fmaf(a, w1.z, p8[6]);
    p8[7] = fmaf(a, w1.w, p8[7]);
  }
  #pragma unroll
  for (int off = 32; off > 0; off >>= 1)
    #pragma unroll
    for (int e = 0; e < 8; e++) p8[e] += __shfl_down(p8[e], off);
  __shared__ float red[4][8];
  int wv = threadIdx.x >> 6;
  if ((threadIdx.x & 63) == 0)
    #pragma unroll
    for (int e = 0; e < 8; e++) red[wv][e] = p8[e];
  __syncthreads();
  if (threadIdx.x < 2) {
    int tok = blockIdx.x * 2 + threadIdx.x;
    float pe[8], m = -1e30f;
    #pragma unroll
    for (int e = 0; e < 8; e++) {
      pe[e] = red[threadIdx.x * 2][e] + red[threadIdx.x * 2 + 1][e];
      m = fmaxf(m, pe[e]);
    }
    float ssum = 0.f;
    #pragma unroll
    for (int e = 0; e < 8; e++) { pe[e] = expf(pe[e] - m); ssum += pe[e]; }
    float inv = 1.0f / ssum;
    #pragma unroll
    for (int e = 0; e < 8; e++) scoresT[e * NTOK + tok] = pe[e] * inv;
  }
}

// ---------------- exact top-2048 per expert: LDS-hist radix + scan tie-break -----
__global__ __launch_bounds__(1024) void select_kernel(const float* __restrict__ scoresT,
    int* __restrict__ idxl, int* __restrict__ slot_of)
{
  int e = blockIdx.x;
  const float* s = scoresT + (size_t)e * NTOK;
  int tid = threadIdx.x;
  int lane = tid & 63, wv = tid >> 6;   // 16 waves

  // load 16 values into registers: value r=j*4+cc has index n = 4*tid + 4096*j + cc
  float4 f[4];
  #pragma unroll
  for (int j = 0; j < 4; j++) f[j] = ((const float4*)s)[tid + 1024 * j];
  unsigned uv[16];
  #pragma unroll
  for (int j = 0; j < 4; j++) {
    uv[j * 4 + 0] = __float_as_uint(f[j].x);
    uv[j * 4 + 1] = __float_as_uint(f[j].y);
    uv[j * 4 + 2] = __float_as_uint(f[j].z);
    uv[j * 4 + 3] = __float_as_uint(f[j].w);
  }

  __shared__ int hist[16][257];
  __shared__ int histsum[256];
  __shared__ int sfx[2][256];
  __shared__ int wsum[16], wpre[16];
  __shared__ int shB, shK, shTot, scnt;

  unsigned prefix = 0;
  int k = CAP_;
  for (int p = 0; p < 4; ++p) {
    int shift = 24 - 8 * p;
    for (int b = tid; b < 16 * 257; b += 1024) ((int*)hist)[b] = 0;
    __syncthreads();
    #pragma unroll
    for (int r = 0; r < 16; r++) {
      unsigned u = uv[r];
      bool match = (p == 0) || ((u >> (shift + 8)) == prefix);
      if (match) atomicAdd(&hist[wv][(u >> shift) & 255], 1);
    }
    __syncthreads();
    if (tid < 256) {
      int tsum = 0;
      #pragma unroll
      for (int w = 0; w < 16; w++) tsum += hist[w][tid];
      histsum[tid] = tsum;
      sfx[0][tid] = tsum;
    }
    __syncthreads();
    // inclusive suffix sum over 256 buckets (Hillis-Steele, 8 steps)
    int cur = 0;
    #pragma unroll
    for (int d = 1; d < 256; d <<= 1) {
      if (tid < 256)
        sfx[cur ^ 1][tid] = sfx[cur][tid] + ((tid + d < 256) ? sfx[cur][tid + d] : 0);
      __syncthreads();
      cur ^= 1;
    }
    if (tid < 256) {
      int sv = sfx[cur][tid];
      int snext = (tid < 255) ? sfx[cur][tid + 1] : 0;
      if (sv >= k && snext < k) { shB = tid; shK = k - snext; }
    }
    __syncthreads();
    prefix = (prefix << 8) | (unsigned)shB;
    k = shK;
    __syncthreads();
  }
  unsigned thr = prefix;
  int kk = k;   // how many of the tied (== thr) values to take, lowest index first

  // ---- output: take = (u > thr) || (u == thr && index-rank among ties < kk) ----
  if (tid == 0) scnt = 0;
  __syncthreads();
  int jb = 0;   // tie-count base over j blocks (n-major ordering: j, then tid, then cc)
  #pragma unroll
  for (int j = 0; j < 4; j++) {
    int eqf[4], c = 0;
    #pragma unroll
    for (int cc = 0; cc < 4; cc++) {
      eqf[cc] = (uv[j * 4 + cc] == thr) ? 1 : 0;
      c += eqf[cc];
    }
    // wave inclusive scan of per-thread tie counts
    int sc = c;
    #pragma unroll
    for (int d = 1; d < 64; d <<= 1) {
      int tt = __shfl_up(sc, d);
      if (lane >= d) sc += tt;
    }
    if (lane == 63) wsum[wv] = sc;
    __syncthreads();
    if (tid == 0) {
      int a = 0;
      #pragma unroll
      for (int w = 0; w < 16; w++) { int t2 = wsum[w]; wpre[w] = a; a += t2; }
      shTot = a;
    }
    __syncthreads();
    int excl = wpre[wv] + (sc - c);   // exclusive prefix of ties for this thread
    int local = 0;
    int sov[4];
    #pragma unroll
    for (int cc = 0; cc < 4; cc++) {
      unsigned u = uv[j * 4 + cc];
      int n = 4 * tid + 4096 * j + cc;
      bool take = (u > thr) || (eqf[cc] && (jb + excl + local) < kk);
      local += eqf[cc];
      unsigned long long msk = __ballot(take);
      int cntw = __popcll(msk);
      int base = 0;
      if (lane == 0 && cntw) base = atomicAdd(&scnt, cntw);
      base = __shfl(base, 0);
      int slot = base + __popcll(msk & ((1ull << lane) - 1ull));
      int sv = -1;
      if (take) {
        idxl[e * CAP_ + slot] = n;
        sv = slot;
      }
      sov[cc] = sv;
    }
    int4 so;
    so.x = sov[0]; so.y = sov[1]; so.z = sov[2]; so.w = sov[3];
    ((int4*)(slot_of + (size_t)e * NTOK))[tid + 1024 * j] = so;
    jb += shTot;
    __syncthreads();
  }
}

// ------- per-expert fp32 GEMM -> yo: global_load_lds staging + 32KB LDS dbuf -----
// GKK=16. A slot s in [0,512): row = s>>2, kqs = s&3, holds
//   A[row][ (kqs ^ (row>>3 & 3))*4 ..+4 )        (XOR swizzle, 2-bit key)
// B slot s in [0,512): kkk = s>>5, cc = s&31, holds B[kkk][cc*4 ..+4)
#define GM 128
#define GN 128
#define GKK 16
__device__ __forceinline__ float comp4(const float4 v, int u) {
  return u == 0 ? v.x : u == 1 ? v.y : u == 2 ? v.z : v.w;
}
__device__ __forceinline__ void gl_lds16(const void* g, void* l) {
  __builtin_amdgcn_global_load_lds(
      (const __attribute__((address_space(1))) unsigned int*)g,
      (__attribute__((address_space(3))) unsigned int*)l, 16, 0, 0);
}
__global__ __launch_bounds__(256) void gemm_kernel(const float* __restrict__ xe,
    const float* __restrict__ ew, const int* __restrict__ idxl, float* __restrict__ yo)
{
  int bid0 = blockIdx.x;
  // XCD swizzle: 512 blocks / 8 XCDs -> each XCD gets one expert (A panel 4MB, L2-fit)
  int bid = (bid0 & 7) * 64 + (bid0 >> 3);
  int e = bid >> 6, rem = bid & 63, mt = rem >> 2, nt = rem & 3;
  __shared__ float4 AB[2 * 1024];   // buf b: A at b*1024, B at b*1024+512 (32 KB total)
  int tid = threadIdx.x;
  int tx = tid & 15, ty = tid >> 4;
  const float* We = ew + (size_t)e * TWOD * TWOD + nt * GN;

  // per-lane pre-swizzled global source pointers; LDS dest is linear (lane-ordered)
  const float* aptr0[2];
  const float* bptr0[2];
  #pragma unroll
  for (int l = 0; l < 2; l++) {
    int slot = l * 256 + tid;
    int row = slot >> 2, kqs = slot & 3;
    int kq = kqs ^ ((row >> 3) & 3);
    int tok = idxl[e * CAP_ + mt * GM + row];
    aptr0[l] = xe + (size_t)tok * TWOD + kq * 4;
    int kkk = slot >> 5, cc = slot & 31;
    bptr0[l] = We + (size_t)kkk * TWOD + cc * 4;
  }
  int wbase = tid & 192;   // wave-uniform: (tid>>6)*64

  // stage tile at k-offset kb (floats) into buffer `buf`
  auto stage = [&](int buf, int kb) {
    float4* dA = AB + buf * 1024 + wbase;
    float4* dB = dA + 512;
    #pragma unroll
    for (int l = 0; l < 2; l++) {
      gl_lds16(aptr0[l] + kb, (void*)(dA + l * 256));
      gl_lds16(bptr0[l] + (size_t)kb * TWOD, (void*)(dB + l * 256));
    }
  };

  stage(0, 0);
  __syncthreads();   // drains vmcnt -> tile 0 resident

  float acc[8][8] = {};   // rows ty*8+i ; cols: jj<4 -> tx*4+jj, jj>=4 -> 64+tx*4+jj-4
  int cur = 0;

  for (int kb = GKK; kb <= TWOD; kb += GKK) {
    if (kb < TWOD) stage(cur ^ 1, kb);   // in-flight across the compute phase
    const float4* As4 = AB + cur * 1024;
    const float4* Bs4 = As4 + 512;
    #pragma unroll
    for (int k4 = 0; k4 < GKK; k4 += 4) {
      int kq = k4 >> 2;
      float4 a4[8], b4[8];
      #pragma unroll
      for (int i = 0; i < 8; i++) a4[i] = As4[(ty * 8 + i) * 4 + (kq ^ (ty & 3))];
      #pragma unroll
      for (int u = 0; u < 4; u++) {
        b4[2 * u]     = Bs4[(k4 + u) * 32 + tx];
        b4[2 * u + 1] = Bs4[(k4 + u) * 32 + 16 + tx];
      }
      #pragma unroll
      for (int u = 0; u < 4; u++) {
        float av[8], bv[8];
        #pragma unroll
        for (int i = 0; i < 8; i++) av[i] = comp4(a4[i], u);
        bv[0] = b4[2*u].x; bv[1] = b4[2*u].y; bv[2] = b4[2*u].z; bv[3] = b4[2*u].w;
        bv[4] = b4[2*u+1].x; bv[5] = b4[2*u+1].y; bv[6] = b4[2*u+1].z; bv[7] = b4[2*u+1].w;
        #pragma unroll
        for (int i = 0; i < 8; i++)
          #pragma unroll
          for (int jj = 0; jj < 8; jj++)
            acc[i][jj] = fmaf(av[i], bv[jj], acc[i][jj]);
      }
    }
    __syncthreads();   // vmcnt drain lands AFTER ~2048 cy of FMA; next tile ready
    cur ^= 1;
  }

  #pragma unroll
  for (int i = 0; i < 8; i++) {
    float* dst = yo + (size_t)(e * CAP_ + mt * GM + ty * 8 + i) * TWOD + nt * GN + tx * 4;
    float4 o0 = {acc[i][0], acc[i][1], acc[i][2], acc[i][3]};
    float4 o1 = {acc[i][4], acc[i][5], acc[i][6], acc[i][7]};
    *(float4*)dst = o0;
    *(float4*)(dst + 64) = o1;
  }
}

// ---------------- combine (gather yo) + state update -----------------------------
__global__ __launch_bounds__(256) void combine_update_kernel(const float4* __restrict__ yo,
    const float* __restrict__ scoresT, const int* __restrict__ slot_of,
    const float4* __restrict__ xt, float4* __restrict__ xs,
    float4* __restrict__ pred, int* __restrict__ counts, float lr, int write_pred)
{
  int q = blockIdx.x * 256 + threadIdx.x;
  int n = q >> 7, dq = q & 127;
  float4 p = {0, 0, 0, 0};
  int cnt = 0;
  #pragma unroll
  for (int e = 0; e < E_; e++) {
    int sl = slot_of[e * NTOK + n];
    if (sl >= 0) {
      float val = scoresT[e * NTOK + n];
      float4 y = yo[(size_t)(e * CAP_ + sl) * 128 + dq];
      p.x = fmaf(val, y.x, p.x);
      p.y = fmaf(val, y.y, p.y);
      p.z = fmaf(val, y.z, p.z);
      p.w = fmaf(val, y.w, p.w);
      cnt++;
    }
  }
  float4 t = xt[q], s = xs[q];
  s.x += lr * fminf(fmaxf(t.x - p.x, -10.f), 10.f);
  s.y += lr * fminf(fmaxf(t.y - p.y, -10.f), 10.f);
  s.z += lr * fminf(fmaxf(t.z - p.z, -10.f), 10.f);
  s.w += lr * fminf(fmaxf(t.w - p.w, -10.f), 10.f);
  xs[q] = s;
  if (write_pred) {
    pred[q] = p;
    if (dq == 0) counts[n] = cnt;
  }
}

// ---------------- combine (gather yo) + final out + res partial -------------------
__global__ __launch_bounds__(256) void combine_final_kernel(const float4* __restrict__ yo,
    const float* __restrict__ scoresT, const int* __restrict__ slot_of,
    const float4* __restrict__ xt, const float4* __restrict__ xs,
    float4* __restrict__ out, float* __restrict__ racc)
{
  int q = blockIdx.x * 256 + threadIdx.x;
  int n = q >> 7, dq = q & 127;
  float4 p = {0, 0, 0, 0};
  #pragma unroll
  for (int e = 0; e < E_; e++) {
    int sl = slot_of[e * NTOK + n];
    if (sl >= 0) {
      float val = scoresT[e * NTOK + n];
      float4 y = yo[(size_t)(e * CAP_ + sl) * 128 + dq];
      p.x = fmaf(val, y.x, p.x);
      p.y = fmaf(val, y.y, p.y);
      p.z = fmaf(val, y.z, p.z);
      p.w = fmaf(val, y.w, p.w);
    }
  }
  float4 t = xt[q], s = xs[q];
  float dr0 = t.x - p.x, di0 = t.y - p.y, dr1 = t.z - p.z, di1 = t.w - p.w;
  float4 o = {s.x + 0.5f * dr0, s.y + 0.5f * di0, s.z + 0.5f * dr1, s.w + 0.5f * di1};
  out[q] = o;
  float lsum = sqrtf(dr0 * dr0 + di0 * di0) + sqrtf(dr1 * dr1 + di1 * di1);
  __shared__ float red[256];
  red[threadIdx.x] = lsum;
  __syncthreads();
  for (int off = 128; off > 0; off >>= 1) {
    if (threadIdx.x < off) red[threadIdx.x] += red[threadIdx.x + off];
    __syncthreads();
  }
  if (threadIdx.x == 0) atomicAdd(racc, red[0]);
}

// ---------------- x_states = tanh(pred / max(counts,1) + bias) -------------------
__global__ __launch_bounds__(256) void activate_kernel(const float4* __restrict__ pred,
    const int* __restrict__ counts, const float4* __restrict__ bias, float4* __restrict__ xs)
{
  int q = blockIdx.x * 256 + threadIdx.x;
  int n = q >> 7;
  float denom = fmaxf((float)counts[n], 1.0f);
  float4 p = pred[q];
  float4 b = bias[q & 127];
  float4 r;
  r.x = tanhf(p.x / denom + b.x);
  r.y = tanhf(p.y / denom + b.y);
  r.z = tanhf(p.z / denom + b.z);
  r.w = tanhf(p.w / denom + b.w);
  xs[q] = r;
}

__global__ void finish_kernel(const float* __restrict__ racc, float* __restrict__ dst)
{
  if (threadIdx.x == 0) dst[0] = racc[0] / 4194304.0f;
}

// ---------------- host launch ----------------------------------------------------
extern "C" void kernel_launch(void* const* d_in, const int* in_sizes, int n_in,
                              void* d_out, int out_size, void* d_ws, size_t ws_size,
                              hipStream_t stream)
{
  const float* x     = (const float*)d_in[0];
  const float* gains = (const float*)d_in[1];
  const float* cosp  = (const float*)d_in[2];
  const float* sinp  = (const float*)d_in[3];
  const float* gw    = (const float*)d_in[4];
  const float* ew    = (const float*)d_in[5];
  const float* bias  = (const float*)d_in[6];
  float* out = (float*)d_out;

  char* w = (char*)d_ws;
  size_t off = 0;
  auto alloc = [&](size_t bytes) -> void* {
    void* p = w + off;
    off += (bytes + 255) & ~(size_t)255;
    return p;
  };
  float* xt      = (float*)alloc((size_t)NTOK * TWOD * 4);
  float* xs      = (float*)alloc((size_t)NTOK * TWOD * 4);
  float* xe      = (float*)alloc((size_t)NTOK * TWOD * 4);
  float* pred    = (float*)alloc((size_t)NTOK * TWOD * 4);
  float* yo      = (float*)alloc((size_t)E_ * CAP_ * TWOD * 4);
  float* scoresT = (float*)alloc((size_t)E_ * NTOK * 4);
  int*   idxl    = (int*)  alloc((size_t)E_ * CAP_ * 4);
  int*   slot_of = (int*)  alloc((size_t)E_ * NTOK * 4);
  int*   counts  = (int*)  alloc((size_t)NTOK * 4);
  float* racc    = (float*)alloc(256);

  const int eb = NQ / 256;  // 8192

  init_kernel<<<eb, 256, 0, stream>>>((const float4*)x, cosp, sinp, (float4*)xt, (float4*)xs);

  double lr = 0.5;
  for (int it = 0; it < 9; ++it) {
    if (it == 8)
      activate_kernel<<<eb, 256, 0, stream>>>((const float4*)pred, counts,
                                              (const float4*)bias, (float4*)xs);
    delays_gate_kernel<<<eb, 256, 0, stream>>>((const float4*)xs, gains, gw,
                                               (float4*)xe, scoresT);
    select_kernel<<<E_, 1024, 0, stream>>>(scoresT, idxl, slot_of);
    gemm_kernel<<<512, 256, 0, stream>>>(xe, ew, idxl, yo);
    if (it < 8) {
      combine_update_kernel<<<eb, 256, 0, stream>>>((const float4*)yo, scoresT, slot_of,
          (const float4*)xt, (float4*)xs, (float4*)pred, counts, (float)lr, it == 7 ? 1 : 0);
      lr *= 0.85;
    } else {
      hipMemsetAsync(racc, 0, 4, stream);
      combine_final_kernel<<<eb, 256, 0, stream>>>((const float4*)yo, scoresT, slot_of,
          (const float4*)xt, (const float4*)xs, (float4*)out, racc);
    }
  }
  finish_kernel<<<1, 64, 0, stream>>>(racc, out + (size_t)NTOK * TWOD);
}